// Round 1
// baseline (254.835 us; speedup 1.0000x reference)
//
#include <hip/hip_runtime.h>
#include <hip/hip_bf16.h>
#include <stdint.h>

#define KN 32
#define D  128

typedef __bf16 bf16;
typedef __bf16 bf16x8 __attribute__((ext_vector_type(8)));
typedef float  f32x4  __attribute__((ext_vector_type(4)));

// LDS row strides (+8 bf16 pad -> row stride = 4 banks mod 32: conflict-free-ish b128 reads)
#define X_STRIDE 264   // 256 + 8
#define H_STRIDE 136   // 128 + 8

// ---------------------------------------------------------------------------
// Pack W1 (128x256) and W2 (128x128) fp32 -> bf16 in MFMA B-fragment order.
// B-frag layout for mfma_f32_16x16x32_bf16: lane holds B[k=quad*8+j][n=lane&15].
// w1p index: ((ntile*8 + ktile)*64 + lane)*8 + j   (ntile in [0,8), ktile in [0,8))
// w2p index: ((ntile*4 + ktile)*64 + lane)*8 + j   (ntile in [0,8), ktile in [0,4))
// B[f][n] = W[n][f]  (einsum contracts over the second index of W)
// ---------------------------------------------------------------------------
__global__ __launch_bounds__(256) void pack_weights_kernel(
    const float* __restrict__ W1, const float* __restrict__ W2,
    bf16* __restrict__ w1p, bf16* __restrict__ w2p)
{
    int t = blockIdx.x * 256 + threadIdx.x;
    if (t < 32768) {
        int j = t & 7, lane = (t >> 3) & 63, kt = (t >> 9) & 7, nt = t >> 12;
        int d = nt * 16 + (lane & 15);
        int f = kt * 32 + ((lane >> 4) << 3) + j;
        w1p[t] = (bf16)W1[d * 256 + f];
    } else if (t < 49152) {
        int u = t - 32768;
        int j = u & 7, lane = (u >> 3) & 63, kt = (u >> 9) & 3, nt = u >> 11;
        int e  = nt * 16 + (lane & 15);
        int dd = kt * 32 + ((lane >> 4) << 3) + j;
        w2p[u] = (bf16)W2[e * 128 + dd];
    }
}

// ---------------------------------------------------------------------------
// One block (256 threads = 4 waves) per node n.
// ---------------------------------------------------------------------------
__global__ __launch_bounds__(256) void graphrec_agg_kernel(
    const int*   __restrict__ nodes,
    const int*   __restrict__ neigh_idx,
    const int*   __restrict__ neigh_len,
    const float* __restrict__ u2e,
    const float* __restrict__ b1,
    const float* __restrict__ b2,
    const float* __restrict__ W3,
    const float* __restrict__ b3,
    const bf16*  __restrict__ w1p,
    const bf16*  __restrict__ w2p,
    float*       __restrict__ out)
{
    __shared__ alignas(16) bf16  x_bf[KN * X_STRIDE];   // A matrix [32 x 256] bf16
    __shared__ alignas(16) bf16  h1_bf[KN * H_STRIDE];  // [32 x 128] bf16
    __shared__ alignas(16) bf16  h2_bf[KN * H_STRIDE];  // [32 x 128] bf16
    __shared__ alignas(16) float eu_f[KN * D];          // fp32 e_u for aggregation
    __shared__ float self_f[D];
    __shared__ float logits_s[KN];
    __shared__ float att_s[KN];

    const int n   = blockIdx.x;
    const int t   = threadIdx.x;
    const int len = neigh_len[n];

    // ---- stage: gather e_u rows (8 threads per row, 16 floats each) ----
    {
        int k  = t >> 3;
        int f0 = (t & 7) << 4;
        int idx = neigh_idx[n * KN + k];
        const float* src = u2e + (size_t)idx * D + f0;
        float4 a0 = *(const float4*)(src);
        float4 a1 = *(const float4*)(src + 4);
        float4 a2 = *(const float4*)(src + 8);
        float4 a3 = *(const float4*)(src + 12);
        float* df = eu_f + k * D + f0;
        *(float4*)(df)      = a0; *(float4*)(df + 4)  = a1;
        *(float4*)(df + 8)  = a2; *(float4*)(df + 12) = a3;
        float vr[16];
        *(float4*)(vr)      = a0; *(float4*)(vr + 4)  = a1;
        *(float4*)(vr + 8)  = a2; *(float4*)(vr + 12) = a3;
        bf16x8 v0, v1;
        #pragma unroll
        for (int i = 0; i < 8; ++i) { v0[i] = (bf16)vr[i]; v1[i] = (bf16)vr[8 + i]; }
        *(bf16x8*)(x_bf + k * X_STRIDE + f0)     = v0;
        *(bf16x8*)(x_bf + k * X_STRIDE + f0 + 8) = v1;
    }
    // ---- stage: self features (fp32 + bf16 broadcast into all 32 A-rows) ----
    if (t < D) {
        int node = nodes[n];
        float s = u2e[(size_t)node * D + t];
        self_f[t] = s;
        bf16 sb = (bf16)s;
        #pragma unroll
        for (int k = 0; k < KN; ++k) x_bf[k * X_STRIDE + D + t] = sb;
    }
    __syncthreads();

    const int lane = t & 63;
    const int wave = t >> 6;
    const int ln15 = lane & 15;
    const int quad = lane >> 4;
    const int nt0  = wave * 2;   // each wave owns N-tiles {nt0, nt0+1}

    // ---- layer 1: [32 x 256] @ [256 x 128] ----
    f32x4 c00 = {0.f,0.f,0.f,0.f}, c01 = c00, c10 = c00, c11 = c00;
    #pragma unroll
    for (int ft = 0; ft < 8; ++ft) {
        bf16x8 a0  = *(const bf16x8*)(x_bf + ln15 * X_STRIDE + ft * 32 + quad * 8);
        bf16x8 a1  = *(const bf16x8*)(x_bf + (16 + ln15) * X_STRIDE + ft * 32 + quad * 8);
        bf16x8 bb0 = *(const bf16x8*)(w1p + (nt0 * 8 + ft) * 512 + lane * 8);
        bf16x8 bb1 = *(const bf16x8*)(w1p + ((nt0 + 1) * 8 + ft) * 512 + lane * 8);
        c00 = __builtin_amdgcn_mfma_f32_16x16x32_bf16(a0, bb0, c00, 0, 0, 0);
        c01 = __builtin_amdgcn_mfma_f32_16x16x32_bf16(a0, bb1, c01, 0, 0, 0);
        c10 = __builtin_amdgcn_mfma_f32_16x16x32_bf16(a1, bb0, c10, 0, 0, 0);
        c11 = __builtin_amdgcn_mfma_f32_16x16x32_bf16(a1, bb1, c11, 0, 0, 0);
    }
    {   // epilogue: relu(c + b1) -> bf16 LDS. C/D map: col=lane&15, row=quad*4+r
        float bias0 = b1[nt0 * 16 + ln15];
        float bias1 = b1[(nt0 + 1) * 16 + ln15];
        #pragma unroll
        for (int r = 0; r < 4; ++r) {
            int row = quad * 4 + r;
            h1_bf[row * H_STRIDE + nt0 * 16 + ln15]              = (bf16)fmaxf(c00[r] + bias0, 0.f);
            h1_bf[row * H_STRIDE + (nt0 + 1) * 16 + ln15]        = (bf16)fmaxf(c01[r] + bias1, 0.f);
            h1_bf[(16 + row) * H_STRIDE + nt0 * 16 + ln15]       = (bf16)fmaxf(c10[r] + bias0, 0.f);
            h1_bf[(16 + row) * H_STRIDE + (nt0 + 1) * 16 + ln15] = (bf16)fmaxf(c11[r] + bias1, 0.f);
        }
    }
    __syncthreads();

    // ---- layer 2: [32 x 128] @ [128 x 128] ----
    f32x4 d00 = {0.f,0.f,0.f,0.f}, d01 = d00, d10 = d00, d11 = d00;
    #pragma unroll
    for (int kt = 0; kt < 4; ++kt) {
        bf16x8 a0  = *(const bf16x8*)(h1_bf + ln15 * H_STRIDE + kt * 32 + quad * 8);
        bf16x8 a1  = *(const bf16x8*)(h1_bf + (16 + ln15) * H_STRIDE + kt * 32 + quad * 8);
        bf16x8 bb0 = *(const bf16x8*)(w2p + (nt0 * 4 + kt) * 512 + lane * 8);
        bf16x8 bb1 = *(const bf16x8*)(w2p + ((nt0 + 1) * 4 + kt) * 512 + lane * 8);
        d00 = __builtin_amdgcn_mfma_f32_16x16x32_bf16(a0, bb0, d00, 0, 0, 0);
        d01 = __builtin_amdgcn_mfma_f32_16x16x32_bf16(a0, bb1, d01, 0, 0, 0);
        d10 = __builtin_amdgcn_mfma_f32_16x16x32_bf16(a1, bb0, d10, 0, 0, 0);
        d11 = __builtin_amdgcn_mfma_f32_16x16x32_bf16(a1, bb1, d11, 0, 0, 0);
    }
    {
        float bias0 = b2[nt0 * 16 + ln15];
        float bias1 = b2[(nt0 + 1) * 16 + ln15];
        #pragma unroll
        for (int r = 0; r < 4; ++r) {
            int row = quad * 4 + r;
            h2_bf[row * H_STRIDE + nt0 * 16 + ln15]              = (bf16)fmaxf(d00[r] + bias0, 0.f);
            h2_bf[row * H_STRIDE + (nt0 + 1) * 16 + ln15]        = (bf16)fmaxf(d01[r] + bias1, 0.f);
            h2_bf[(16 + row) * H_STRIDE + nt0 * 16 + ln15]       = (bf16)fmaxf(d10[r] + bias0, 0.f);
            h2_bf[(16 + row) * H_STRIDE + (nt0 + 1) * 16 + ln15] = (bf16)fmaxf(d11[r] + bias1, 0.f);
        }
    }
    __syncthreads();

    // ---- logits: logit[k] = W3 . h2[k] + b3  (8 threads per k) ----
    {
        int k = t >> 3;
        int j = t & 7;
        const bf16* hr = h2_bf + k * H_STRIDE + j * 16;
        float p = 0.f;
        #pragma unroll
        for (int i = 0; i < 16; ++i) p += (float)hr[i] * W3[j * 16 + i];
        p += __shfl_xor(p, 1);
        p += __shfl_xor(p, 2);
        p += __shfl_xor(p, 4);
        if (j == 0) logits_s[k] = p + b3[0];
    }
    __syncthreads();

    // ---- masked softmax over K (lanes 0..31 of wave 0) ----
    if (t < 64) {
        int k = lane & 31;
        bool act = (lane < 32) && (k < len);
        float l = act ? logits_s[k] : -1e30f;
        float m = l;
        #pragma unroll
        for (int o = 1; o < 32; o <<= 1) m = fmaxf(m, __shfl_xor(m, o));
        float e = act ? expf(l - m) : 0.f;
        float s = e;
        #pragma unroll
        for (int o = 1; o < 32; o <<= 1) s += __shfl_xor(s, o);
        if (lane < 32) att_s[k] = (s > 0.f) ? (e / s) : 0.f;
    }
    __syncthreads();

    // ---- aggregation (fp32): out = has_neigh ? 0.5*(sum_k att*e_u + self) : self ----
    if (t < D) {
        float a = 0.f;
        #pragma unroll
        for (int k = 0; k < KN; ++k) a += att_s[k] * eu_f[k * D + t];
        float sf = self_f[t];
        out[(size_t)n * D + t] = (len > 0) ? 0.5f * (a + sf) : sf;
    }
}

extern "C" void kernel_launch(void* const* d_in, const int* in_sizes, int n_in,
                              void* d_out, int out_size, void* d_ws, size_t ws_size,
                              hipStream_t stream) {
    const int*   nodes     = (const int*)d_in[0];
    const int*   neigh_idx = (const int*)d_in[1];
    const int*   neigh_len = (const int*)d_in[2];
    const float* u2e       = (const float*)d_in[3];
    const float* W1        = (const float*)d_in[4];
    const float* b1        = (const float*)d_in[5];
    const float* W2        = (const float*)d_in[6];
    const float* b2        = (const float*)d_in[7];
    const float* W3        = (const float*)d_in[8];
    const float* b3        = (const float*)d_in[9];
    float* out = (float*)d_out;

    bf16* w1p = (bf16*)d_ws;          // 32768 bf16 = 64 KB
    bf16* w2p = w1p + 32768;          // 16384 bf16 = 32 KB

    const int n = in_sizes[0];        // 20000 nodes

    pack_weights_kernel<<<192, 256, 0, stream>>>(W1, W2, w1p, w2p);
    graphrec_agg_kernel<<<n, 256, 0, stream>>>(nodes, neigh_idx, neigh_len, u2e,
                                               b1, b2, W3, b3, w1p, w2p, out);
}

// Round 2
// 235.318 us; speedup vs baseline: 1.0829x; 1.0829x over previous
//
#include <hip/hip_runtime.h>
#include <hip/hip_bf16.h>
#include <stdint.h>

#define KN 32
#define D  128
#define NNODES 20000
#define GRID 2500          // 20000/2500 = exactly 8 nodes per block, perfectly balanced

typedef __bf16 bf16;
typedef __bf16 bf16x8 __attribute__((ext_vector_type(8)));
typedef float  f32x4  __attribute__((ext_vector_type(4)));

// LDS row strides (bf16 elements). 136*2B = 272 B = 68 dwords, 68 % 32 = 4 -> even
// 8-accesses-per-bank on b128 ops (minimum for wave64). eu_f padded to 132 floats
// (132 % 32 = 4) -- unpadded 128 concentrated all gather writes on banks {0,16}.
#define X_STRIDE  136   // x_bf: e_u half only (cols 0..127)
#define H_STRIDE  136
#define EU_STRIDE 132

// ---------------------------------------------------------------------------
// Pack W1 (128x256) and W2 (128x128) fp32 -> bf16 in MFMA B-fragment order.
// B-frag for mfma_f32_16x16x32_bf16: lane holds B[k=quad*8+j][n=lane&15].
// w1p index: ((nt*8 + ft)*64 + lane)*8 + j   (nt in [0,8), ft in [0,8))
// w2p index: ((nt*4 + kt)*64 + lane)*8 + j   (nt in [0,8), kt in [0,4))
// ---------------------------------------------------------------------------
__global__ __launch_bounds__(256) void pack_weights_kernel(
    const float* __restrict__ W1, const float* __restrict__ W2,
    bf16* __restrict__ w1p, bf16* __restrict__ w2p)
{
    int t = blockIdx.x * 256 + threadIdx.x;
    if (t < 32768) {
        int j = t & 7, lane = (t >> 3) & 63, kt = (t >> 9) & 7, nt = t >> 12;
        int d = nt * 16 + (lane & 15);
        int f = kt * 32 + ((lane >> 4) << 3) + j;
        w1p[t] = (bf16)W1[d * 256 + f];
    } else if (t < 49152) {
        int u = t - 32768;
        int j = u & 7, lane = (u >> 3) & 63, kt = (u >> 9) & 3, nt = u >> 11;
        int e  = nt * 16 + (lane & 15);
        int dd = kt * 32 + ((lane >> 4) << 3) + j;
        w2p[u] = (bf16)W2[e * 128 + dd];
    }
}

// ---------------------------------------------------------------------------
// 256 threads = 4 waves per block; each block grid-strides over 8 nodes with
// all MFMA B-fragments (W1,W2) held in VGPRs (loaded once per block).
// __launch_bounds__(256,3): cap VGPRs at 170 so 3 blocks/CU stay resident.
// ---------------------------------------------------------------------------
__global__ __launch_bounds__(256, 3) void graphrec_agg_kernel(
    const int*   __restrict__ nodes,
    const int*   __restrict__ neigh_idx,
    const int*   __restrict__ neigh_len,
    const float* __restrict__ u2e,
    const float* __restrict__ b1,
    const float* __restrict__ b2,
    const float* __restrict__ W3,
    const float* __restrict__ b3,
    const bf16*  __restrict__ w1p,
    const bf16*  __restrict__ w2p,
    float*       __restrict__ out)
{
    __shared__ alignas(16) bf16  x_bf[KN * X_STRIDE];    // e_u bf16 [32 x 128(+8)]
    __shared__ alignas(16) bf16  h1_bf[KN * H_STRIDE];   // [32 x 128(+8)]
    __shared__ alignas(16) float eu_f[KN * EU_STRIDE];   // e_u fp32 for aggregation
    __shared__ alignas(16) float self_f[D];
    __shared__ alignas(16) bf16  self_bf[D];
    __shared__ float lpart[4 * KN];                      // per-wave logit partials
    __shared__ float att_s[KN];

    const int t    = threadIdx.x;
    const int lane = t & 63;
    const int wave = t >> 6;
    const int ln15 = lane & 15;
    const int quad = lane >> 4;
    const int nt0  = wave * 2;   // this wave's two N-tiles (of 8)

    // ---- loop-invariant per-thread scalars ----
    const float bias1_0 = b1[nt0 * 16 + ln15];
    const float bias1_1 = b1[(nt0 + 1) * 16 + ln15];
    const float bias2_0 = b2[nt0 * 16 + ln15];
    const float bias2_1 = b2[(nt0 + 1) * 16 + ln15];
    const float w3_0    = W3[nt0 * 16 + ln15];
    const float w3_1    = W3[(nt0 + 1) * 16 + ln15];
    const float b3v     = b3[0];

    // ---- load all B-fragments into registers, once ----
    bf16x8 w1r[2][8];
    #pragma unroll
    for (int nt = 0; nt < 2; ++nt)
        #pragma unroll
        for (int ft = 0; ft < 8; ++ft)
            w1r[nt][ft] = *(const bf16x8*)(w1p + ((nt0 + nt) * 8 + ft) * 512 + lane * 8);
    bf16x8 w2r[2][4];
    #pragma unroll
    for (int nt = 0; nt < 2; ++nt)
        #pragma unroll
        for (int kt = 0; kt < 4; ++kt)
            w2r[nt][kt] = *(const bf16x8*)(w2p + ((nt0 + nt) * 4 + kt) * 512 + lane * 8);

    for (int n = blockIdx.x; n < NNODES; n += GRID) {
        const int len = neigh_len[n];

        // ---- gather: e_u rows (8 threads/row, 16 floats each) + self ----
        {
            int k  = t >> 3;
            int f0 = (t & 7) << 4;
            int idx = neigh_idx[n * KN + k];
            const float* src = u2e + (size_t)idx * D + f0;
            float4 a0 = *(const float4*)(src);
            float4 a1 = *(const float4*)(src + 4);
            float4 a2 = *(const float4*)(src + 8);
            float4 a3 = *(const float4*)(src + 12);
            float* df = eu_f + k * EU_STRIDE + f0;
            *(float4*)(df)      = a0; *(float4*)(df + 4)  = a1;
            *(float4*)(df + 8)  = a2; *(float4*)(df + 12) = a3;
            float vr[16];
            *(float4*)(vr)      = a0; *(float4*)(vr + 4)  = a1;
            *(float4*)(vr + 8)  = a2; *(float4*)(vr + 12) = a3;
            bf16x8 v0, v1;
            #pragma unroll
            for (int i = 0; i < 8; ++i) { v0[i] = (bf16)vr[i]; v1[i] = (bf16)vr[8 + i]; }
            *(bf16x8*)(x_bf + k * X_STRIDE + f0)     = v0;
            *(bf16x8*)(x_bf + k * X_STRIDE + f0 + 8) = v1;
        }
        if (t < D) {
            float s = u2e[(size_t)nodes[n] * D + t];
            self_f[t]  = s;
            self_bf[t] = (bf16)s;
        }
        __syncthreads();

        // self-half A-fragments: identical for all 16 rows (broadcast read)
        bf16x8 sa[4];
        #pragma unroll
        for (int i = 0; i < 4; ++i)
            sa[i] = *(const bf16x8*)(self_bf + i * 32 + quad * 8);

        // ---- layer 1: [32 x 256] @ [256 x 128], B in registers ----
        f32x4 c00 = {0.f,0.f,0.f,0.f}, c01 = c00, c10 = c00, c11 = c00;
        #pragma unroll
        for (int ft = 0; ft < 4; ++ft) {
            bf16x8 a0 = *(const bf16x8*)(x_bf + ln15 * X_STRIDE + ft * 32 + quad * 8);
            bf16x8 a1 = *(const bf16x8*)(x_bf + (16 + ln15) * X_STRIDE + ft * 32 + quad * 8);
            c00 = __builtin_amdgcn_mfma_f32_16x16x32_bf16(a0, w1r[0][ft], c00, 0, 0, 0);
            c01 = __builtin_amdgcn_mfma_f32_16x16x32_bf16(a0, w1r[1][ft], c01, 0, 0, 0);
            c10 = __builtin_amdgcn_mfma_f32_16x16x32_bf16(a1, w1r[0][ft], c10, 0, 0, 0);
            c11 = __builtin_amdgcn_mfma_f32_16x16x32_bf16(a1, w1r[1][ft], c11, 0, 0, 0);
        }
        #pragma unroll
        for (int ft = 4; ft < 8; ++ft) {   // self half: same A for both row-tiles
            bf16x8 a = sa[ft - 4];
            c00 = __builtin_amdgcn_mfma_f32_16x16x32_bf16(a, w1r[0][ft], c00, 0, 0, 0);
            c01 = __builtin_amdgcn_mfma_f32_16x16x32_bf16(a, w1r[1][ft], c01, 0, 0, 0);
            c10 = __builtin_amdgcn_mfma_f32_16x16x32_bf16(a, w1r[0][ft], c10, 0, 0, 0);
            c11 = __builtin_amdgcn_mfma_f32_16x16x32_bf16(a, w1r[1][ft], c11, 0, 0, 0);
        }
        {   // relu(c + b1) -> bf16 LDS. C/D map: col=lane&15, row=quad*4+r
            #pragma unroll
            for (int r = 0; r < 4; ++r) {
                int row = quad * 4 + r;
                h1_bf[row * H_STRIDE + nt0 * 16 + ln15]              = (bf16)fmaxf(c00[r] + bias1_0, 0.f);
                h1_bf[row * H_STRIDE + (nt0 + 1) * 16 + ln15]        = (bf16)fmaxf(c01[r] + bias1_1, 0.f);
                h1_bf[(16 + row) * H_STRIDE + nt0 * 16 + ln15]       = (bf16)fmaxf(c10[r] + bias1_0, 0.f);
                h1_bf[(16 + row) * H_STRIDE + (nt0 + 1) * 16 + ln15] = (bf16)fmaxf(c11[r] + bias1_1, 0.f);
            }
        }
        __syncthreads();

        // ---- layer 2: [32 x 128] @ [128 x 128], B in registers ----
        f32x4 d00 = {0.f,0.f,0.f,0.f}, d01 = d00, d10 = d00, d11 = d00;
        #pragma unroll
        for (int kt = 0; kt < 4; ++kt) {
            bf16x8 a0 = *(const bf16x8*)(h1_bf + ln15 * H_STRIDE + kt * 32 + quad * 8);
            bf16x8 a1 = *(const bf16x8*)(h1_bf + (16 + ln15) * H_STRIDE + kt * 32 + quad * 8);
            d00 = __builtin_amdgcn_mfma_f32_16x16x32_bf16(a0, w2r[0][kt], d00, 0, 0, 0);
            d01 = __builtin_amdgcn_mfma_f32_16x16x32_bf16(a0, w2r[1][kt], d01, 0, 0, 0);
            d10 = __builtin_amdgcn_mfma_f32_16x16x32_bf16(a1, w2r[0][kt], d10, 0, 0, 0);
            d11 = __builtin_amdgcn_mfma_f32_16x16x32_bf16(a1, w2r[1][kt], d11, 0, 0, 0);
        }
        {   // fused logit epilogue: h2 never materialized.
            // p[row] = sum_col W3[col]*relu(d+b2); reduce over ln15 (16 lanes).
            #pragma unroll
            for (int r = 0; r < 4; ++r) {
                float p0 = w3_0 * fmaxf(d00[r] + bias2_0, 0.f)
                         + w3_1 * fmaxf(d01[r] + bias2_1, 0.f);   // row quad*4+r
                float p1 = w3_0 * fmaxf(d10[r] + bias2_0, 0.f)
                         + w3_1 * fmaxf(d11[r] + bias2_1, 0.f);   // row 16+quad*4+r
                #pragma unroll
                for (int o = 1; o < 16; o <<= 1) {
                    p0 += __shfl_xor(p0, o);
                    p1 += __shfl_xor(p1, o);
                }
                if (ln15 == 0) {
                    lpart[wave * KN + quad * 4 + r]      = p0;
                    lpart[wave * KN + 16 + quad * 4 + r] = p1;
                }
            }
        }
        __syncthreads();

        // ---- logits sum + masked softmax (lanes 0..31 of wave 0) ----
        if (t < 64) {
            int k = t & 31;
            float lg = lpart[k] + lpart[KN + k] + lpart[2 * KN + k] + lpart[3 * KN + k] + b3v;
            bool act = (t < 32) && (k < len);
            float l = act ? lg : -1e30f;
            float m = l;
            #pragma unroll
            for (int o = 1; o < 32; o <<= 1) m = fmaxf(m, __shfl_xor(m, o));
            float e = act ? expf(l - m) : 0.f;
            float s = e;
            #pragma unroll
            for (int o = 1; o < 32; o <<= 1) s += __shfl_xor(s, o);
            if (t < 32) att_s[k] = (s > 0.f) ? (e / s) : 0.f;
        }
        __syncthreads();

        // ---- aggregation (fp32) ----
        if (t < D) {
            float a = 0.f;
            #pragma unroll
            for (int k = 0; k < KN; ++k) a += att_s[k] * eu_f[k * EU_STRIDE + t];
            float sf = self_f[t];
            out[(size_t)n * D + t] = (len > 0) ? 0.5f * (a + sf) : sf;
        }
        __syncthreads();   // protect x_bf/eu_f/self before next iteration's gather
    }
}

extern "C" void kernel_launch(void* const* d_in, const int* in_sizes, int n_in,
                              void* d_out, int out_size, void* d_ws, size_t ws_size,
                              hipStream_t stream) {
    const int*   nodes     = (const int*)d_in[0];
    const int*   neigh_idx = (const int*)d_in[1];
    const int*   neigh_len = (const int*)d_in[2];
    const float* u2e       = (const float*)d_in[3];
    const float* W1        = (const float*)d_in[4];
    const float* b1        = (const float*)d_in[5];
    const float* W2        = (const float*)d_in[6];
    const float* b2        = (const float*)d_in[7];
    const float* W3        = (const float*)d_in[8];
    const float* b3        = (const float*)d_in[9];
    float* out = (float*)d_out;

    bf16* w1p = (bf16*)d_ws;          // 32768 bf16 = 64 KB
    bf16* w2p = w1p + 32768;          // 16384 bf16 = 32 KB

    pack_weights_kernel<<<192, 256, 0, stream>>>(W1, W2, w1p, w2p);
    graphrec_agg_kernel<<<GRID, 256, 0, stream>>>(nodes, neigh_idx, neigh_len, u2e,
                                                  b1, b2, W3, b3, w1p, w2p, out);
}